// Round 8
// baseline (201.854 us; speedup 1.0000x reference)
//
#include <hip/hip_runtime.h>

// FlashAttention fwd, causal, no scale. B=2,H=16,S=2048,D=128, fp32 in/out.
// R4 design: S^T orientation (mfma(kf,qf)) so each lane owns a full query row.
// R9: exp2 domain + tree reduce + T13 defer-max + pkrtz (83.4us @BM=64).
// R11: BM=128, 8 waves, grid 512; staging per wave halved. 80.3us.
//   Post-mortem: wall == critical WG (qb=15, 32 solo iters) x ~6000cy/iter;
//   2 barriers/iter lockstep + mid-iter vmcnt drain are the serial overhead.
// R12: single-barrier double-buffer, occupancy-neutral at 512 threads:
//   2x(K 16K + V 16K) + P 16K = 80KB -> still 2 WG/CU (grid=2/CU anyway).
//   Per iter: issue kt+1 loads -> QK^T[cur] -> softmax (NO barrier before!)
//   -> PV[cur] -> ds_write kt+1 into buf[cur^1] (vmcnt covered by whole
//   iteration) -> ONE __syncthreads. Waves slip within iteration -> MFMA of
//   one wave hides softmax of another on the same SIMD.
//   Race audit: iter-i writes buf[cur^1] vs iter-i reads buf[cur] disjoint;
//   fast-wave iter-i+1 writes buf[cur] vs slow-wave iter-i reads buf[cur]
//   separated by the iter-i barrier; same-wave order via barrier lgkmcnt.
// History: R1 bf16 fail; R2 scratch demotion; R3 244; R4 94/215; R5 dbuf@256t
// 102 (occupancy halved -- the 512t version fixes that); R6 86.5; R7/R8
// permlane swap-with-self fail; R9 83.4/205; R10 89; R11 80.3/201.7.

#define SQ 2048
#define DH 128
#define BM 128
#define BN 64
#define NELEM 8388608   // B*H*S*D

typedef _Float16 f16x8 __attribute__((ext_vector_type(8)));
typedef float f32x4 __attribute__((ext_vector_type(4)));
typedef unsigned short u16x8 __attribute__((ext_vector_type(8)));
typedef unsigned int u32x4 __attribute__((ext_vector_type(4)));
typedef unsigned int u32x2 __attribute__((ext_vector_type(2)));

__device__ __forceinline__ unsigned short f2h(float f) {
  return __builtin_bit_cast(unsigned short, (_Float16)f);   // v_cvt_f16_f32 RNE
}

// ---------------- pre-kernel: K fp32->fp16 flat; V fp32 -> Vt[bh][d][s] fp16
__global__ __launch_bounds__(256) void prep(const float* __restrict__ k,
                                            const float* __restrict__ v,
                                            unsigned short* __restrict__ ko,
                                            unsigned short* __restrict__ vt) {
  const int tid = threadIdx.x;
  const int bx = blockIdx.x;
  if (bx < 1024) {
    // V transpose tile: 64 s x 128 d
    __shared__ unsigned short lv[64 * 132];   // pad 128->132 to break bank stride
    const int bh = bx >> 5;
    const int s0 = (bx & 31) * 64;
    const float* vs = v + ((size_t)bh * SQ + s0) * DH;
    #pragma unroll
    for (int it = 0; it < 8; ++it) {
      int fi = it * 256 + tid;
      int sL = fi >> 5;
      int dL = (fi & 31) * 4;
      float4 val = *(const float4*)(vs + (size_t)sL * DH + dL);
      ushort4 o;
      o.x = f2h(val.x); o.y = f2h(val.y); o.z = f2h(val.z); o.w = f2h(val.w);
      *(ushort4*)(lv + sL * 132 + dL) = o;
    }
    __syncthreads();
    // store: consecutive lanes cover consecutive s (128B segments per d-row)
    #pragma unroll
    for (int it = 0; it < 4; ++it) {
      int ci = it * 256 + tid;     // 1024 chunks: dL = ci>>3, sg = ci&7
      int dL = ci >> 3;
      int sg = ci & 7;
      u16x8 o;
      #pragma unroll
      for (int j = 0; j < 8; ++j) o[j] = lv[(sg * 8 + j) * 132 + dL];
      *(u16x8*)(vt + ((size_t)bh * DH + dL) * SQ + s0 + sg * 8) = o;
    }
  } else {
    // K conversion: 2048 blocks grid-stride over NELEM/4 float4 chunks
    const int NT = NELEM / 4;
    for (int i = (bx - 1024) * 256 + tid; i < NT; i += 2048 * 256) {
      float4 val = ((const float4*)k)[i];
      ushort4 o;
      o.x = f2h(val.x); o.y = f2h(val.y); o.z = f2h(val.z); o.w = f2h(val.w);
      ((ushort4*)ko)[i] = o;
    }
  }
}

// ---------------- main flash-attention kernel ----------------
// Grid 512, 512 threads (8 waves). xcd = t&7 owns bh in [xcd*4, xcd*4+4);
// per-XCD: cu = (t>>3)&31 -> bh_l = cu>>3, j = cu&7; round (t>>8): qb = j or
// 15-j, so each CU's 2 WGs total 34 kt-units.
// LDS map: buf0 {K [0,16K), V [16K,32K)}, buf1 {K [32K,48K), V [48K,64K)},
//          sP [64K,80K) = 2KB/wave. Q prologue stages into buf0 region.
__global__ __launch_bounds__(512, 4) void fattn(const float* __restrict__ Qf,
                                                const unsigned short* __restrict__ Kh,
                                                const unsigned short* __restrict__ Vth,
                                                float* __restrict__ Out) {
  __shared__ char smem[81920];
  const int tid  = threadIdx.x;
  const int wave = tid >> 6;                // 0..7
  const int lane = tid & 63;
  const int quad = lane >> 4;
  const int c    = lane & 15;

  // block swizzle: XCD bh-affinity + per-CU (j, 15-j) pairing
  const int t     = (int)blockIdx.x;
  const int xcd   = t & 7;
  const int idx   = t >> 3;                 // 0..63
  const int cu    = idx & 31;
  const int round = idx >> 5;               // 0..1
  const int bh_l  = cu >> 3;                // 0..3
  const int j     = cu & 7;
  const int qb    = round ? (15 - j) : j;   // 0..15
  const int bh    = xcd * 4 + bh_l;
  const int rowbase = qb * BM;

  char* sP = smem + 65536 + wave * 2048;

  // ---- stage Q (fp32 -> fp16, pre-scaled by log2e) into buf0 region ----
  const float L2E = 1.44269504088896f;
  const float* Qg = Qf + ((size_t)bh * SQ + rowbase) * DH;
  #pragma unroll
  for (int it = 0; it < 8; ++it) {
    int gi  = it * 512 + tid;      // 4096 units of 4 floats (128 rows x 32)
    int row = gi >> 5;             // 0..127
    int sub = gi & 31;             // 4-float unit within row
    float4 qv = *(const float4*)(Qg + (size_t)row * DH + sub * 4);
    ushort4 h;
    h.x = f2h(qv.x * L2E); h.y = f2h(qv.y * L2E);
    h.z = f2h(qv.z * L2E); h.w = f2h(qv.w * L2E);
    int gr = (sub >> 1) ^ (row & 7);        // 16B-group swizzle
    *(ushort4*)(smem + row * 256 + gr * 16 + (sub & 1) * 8) = h;
  }
  __syncthreads();
  f16x8 qf[4];
  {
    int rl = wave * 16 + c;                 // wave's row (tile-local, 0..127)
    #pragma unroll
    for (int ch = 0; ch < 4; ++ch) {
      int gr = (ch * 4 + quad) ^ (c & 7);   // rl&7 == c&7
      qf[ch] = *(const f16x8*)(smem + rl * 256 + gr * 16);
    }
  }

  // ---- per-thread staging source bases (kt=0); invariant across it-steps:
  // K: 1024 chunks, key = it*32 + (tid>>4), dg = (tid&15)^(key&7) (32%8==0)
  // V: 1024 chunks, d = it*64 + (tid>>3),  kg = (tid&7)^(d&7)     (64%8==0)
  const unsigned short* Kbase = Kh + (size_t)bh * SQ * DH;
  const unsigned short* Vbase = Vth + (size_t)bh * DH * SQ;
  const unsigned short* Ksrc = Kbase + (size_t)(tid >> 4) * DH
                             + ((tid & 15) ^ ((tid >> 4) & 7)) * 8;
  const unsigned short* Vsrc = Vbase + (size_t)(tid >> 3) * SQ
                             + ((tid & 7) ^ ((tid >> 3) & 7)) * 8;

  // ---- kt=0 tile -> regs (issued while Q-region still being read) ----
  u32x4 kreg[2], vreg[2];
  #pragma unroll
  for (int it = 0; it < 2; ++it)
    kreg[it] = *(const u32x4*)(Ksrc + it * (32 * DH));
  #pragma unroll
  for (int it = 0; it < 2; ++it)
    vreg[it] = *(const u32x4*)(Vsrc + it * (64 * SQ));
  __syncthreads();   // all waves done reading Q area (loads in flight)

  // ---- write kt=0 into buf0 (linear dest, pre-swizzled source order) ----
  #pragma unroll
  for (int it = 0; it < 2; ++it)
    *(u32x4*)(smem + it * 8192 + tid * 16) = kreg[it];
  #pragma unroll
  for (int it = 0; it < 2; ++it)
    *(u32x4*)(smem + 16384 + it * 8192 + tid * 16) = vreg[it];
  __syncthreads();

  f32x4 acc[8];                             // O^T: d = dt*16+quad*4+r, row = c
  #pragma unroll
  for (int dt = 0; dt < 8; ++dt) acc[dt] = (f32x4){0.f, 0.f, 0.f, 0.f};
  float mo = -1e30f, lrow = 0.f;            // row stats, log2 domain (row = c)

  const int nkt = 2 * qb + 2;
  int cur = 0;
  for (int kt = 0; kt < nkt; ++kt) {
    const bool hn = (kt + 1 < nkt);
    char* sK = smem + (cur << 15);
    char* sV = sK + 16384;

    // ---- prefetch kt+1 into REGISTERS; vmcnt wait lands at the ds_write
    // AFTER PV (covered by the whole iteration's compute) ----
    if (hn) {
      const unsigned short* Kn = Ksrc + (size_t)(kt + 1) * (BN * DH);
      const unsigned short* Vn = Vsrc + (size_t)(kt + 1) * BN;
      #pragma unroll
      for (int it = 0; it < 2; ++it)
        kreg[it] = *(const u32x4*)(Kn + it * (32 * DH));
      #pragma unroll
      for (int it = 0; it < 2; ++it)
        vreg[it] = *(const u32x4*)(Vn + it * (64 * SQ));
    }
    __builtin_amdgcn_sched_barrier(0);   // pin load issue before compute

    // ---- diagonal classification (two boundary kt tiles per block) ----
    const bool dg1 = (kt == 2 * qb);        // rows 0..63 on diagonal
    const bool dg2 = (kt == 2 * qb + 1);    // rows 64..127 on diagonal
    int ntmax = 3, chmax = 1, rl = 1000;    // defaults: full, no mask
    if (dg1 && wave < 4) { ntmax = wave; chmax = wave >> 1; rl = wave * 16 + c; }
    if (dg2) {
      int w2 = wave - 4;
      if (w2 < 0) { ntmax = -1; chmax = -1; rl = -1; }       // fully masked
      else        { ntmax = w2; chmax = w2 >> 1; rl = w2 * 16 + c; }
    }

    // ---- S^T = K Q^T: D[m=key][n=row]; col=c=row, key = nt*16+quad*4+r ----
    f32x4 sc[4];
    #pragma unroll
    for (int nt = 0; nt < 4; ++nt) sc[nt] = (f32x4){0.f, 0.f, 0.f, 0.f};
    __builtin_amdgcn_s_setprio(1);
    #pragma unroll
    for (int nt = 0; nt < 4; ++nt) {
      if (nt <= ntmax) {
        int keyl = nt * 16 + c;
        #pragma unroll
        for (int ch = 0; ch < 4; ++ch) {
          int gr = (ch * 4 + quad) ^ (c & 7);   // keyl&7 == c&7
          f16x8 kf = *(const f16x8*)(sK + keyl * 256 + gr * 16);
          sc[nt] = __builtin_amdgcn_mfma_f32_16x16x32_f16(kf, qf[ch], sc[nt], 0, 0, 0);
        }
      }
    }
    __builtin_amdgcn_s_setprio(0);

    // ---- causal mask (rl=1000: none; rl=-1: all; else diagonal) ----
    // NO barrier here: sK/sV[cur] stay valid all iteration (dbuf).
    if (rl < 1000) {
      #pragma unroll
      for (int nt = 0; nt < 4; ++nt)
        #pragma unroll
        for (int r = 0; r < 4; ++r)
          if (nt * 16 + quad * 4 + r > rl) sc[nt][r] = -1e30f;
    }

    // ---- online softmax (log2 domain): tree-max + shfl_xor quad reduce ----
    f32x4 ta, tb;
    #pragma unroll
    for (int r = 0; r < 4; ++r) {
      ta[r] = fmaxf(sc[0][r], sc[1][r]);
      tb[r] = fmaxf(sc[2][r], sc[3][r]);
    }
    float cm = fmaxf(fmaxf(fmaxf(ta[0], tb[0]), fmaxf(ta[1], tb[1])),
                     fmaxf(fmaxf(ta[2], tb[2]), fmaxf(ta[3], tb[3])));
    cm = fmaxf(cm, __shfl_xor(cm, 16));
    cm = fmaxf(cm, __shfl_xor(cm, 32));
    const bool keep = __all(cm <= mo + 8.0f) != 0;   // T13 defer-max, P<=2^8
    const float mn = keep ? mo : fmaxf(mo, cm);

    float ps[4];
    u32x2 pkd[4];
    #pragma unroll
    for (int nt = 0; nt < 4; ++nt) {
      float p0 = __builtin_amdgcn_exp2f(sc[nt][0] - mn);
      float p1 = __builtin_amdgcn_exp2f(sc[nt][1] - mn);
      float p2 = __builtin_amdgcn_exp2f(sc[nt][2] - mn);
      float p3 = __builtin_amdgcn_exp2f(sc[nt][3] - mn);
      ps[nt] = (p0 + p1) + (p2 + p3);
      pkd[nt][0] = __builtin_bit_cast(unsigned int, __builtin_amdgcn_cvt_pkrtz(p0, p1));
      pkd[nt][1] = __builtin_bit_cast(unsigned int, __builtin_amdgcn_cvt_pkrtz(p2, p3));
    }
    float rs = (ps[0] + ps[1]) + (ps[2] + ps[3]);
    rs += __shfl_xor(rs, 16);
    rs += __shfl_xor(rs, 32);

    // ---- P write first (LDS latency overlaps rescale below) ----
    #pragma unroll
    for (int nt = 0; nt < 4; ++nt) {
      int g8 = nt * 2 + (quad >> 1);
      *(u32x2*)(sP + c * 128 + ((g8 ^ (c & 7)) * 16) + (quad & 1) * 8) = pkd[nt];
    }

    if (keep) {
      lrow += rs;            // mn == mo everywhere: no rescale needed
    } else {
      const float al = __builtin_amdgcn_exp2f(mo - mn);
      lrow = lrow * al + rs;
      mo = mn;
      #pragma unroll
      for (int dt = 0; dt < 8; ++dt) acc[dt] *= al;
    }

    // ---- O^T += Vt * P: A = Vt frags, B = P frags ----
    __builtin_amdgcn_s_setprio(1);
    #pragma unroll
    for (int ch = 0; ch < 2; ++ch) {
      if (ch <= chmax) {
        f16x8 pf = *(const f16x8*)(sP + c * 128 + (((ch * 4 + quad) ^ (c & 7)) * 16));
        #pragma unroll
        for (int dt = 0; dt < 8; ++dt) {
          int d  = dt * 16 + c;
          int gr = (ch * 4 + quad) ^ (c & 7);   // d&7 == c&7
          f16x8 vf = *(const f16x8*)(sV + d * 128 + gr * 16);
          acc[dt] = __builtin_amdgcn_mfma_f32_16x16x32_f16(vf, pf, acc[dt], 0, 0, 0);
        }
      }
    }
    __builtin_amdgcn_s_setprio(0);

    // ---- stage kt+1 into the OTHER buffer; single barrier per iteration ----
    if (hn) {
      char* nK = smem + ((cur ^ 1) << 15);
      #pragma unroll
      for (int it = 0; it < 2; ++it)
        *(u32x4*)(nK + it * 8192 + tid * 16) = kreg[it];
      #pragma unroll
      for (int it = 0; it < 2; ++it)
        *(u32x4*)(nK + 16384 + it * 8192 + tid * 16) = vreg[it];
      __syncthreads();   // publishes buf[cur^1]; fences buf[cur] reuse
    }
    cur ^= 1;
  }

  // ---- epilogue: O[row][d] = acc / l; float4 per dt ----
  const float inv = 1.0f / lrow;
  const int rowg = rowbase + wave * 16 + c;
  float* op = Out + ((size_t)bh * SQ + rowg) * DH;
  #pragma unroll
  for (int dt = 0; dt < 8; ++dt) {
    float4 o;
    o.x = acc[dt][0] * inv;
    o.y = acc[dt][1] * inv;
    o.z = acc[dt][2] * inv;
    o.w = acc[dt][3] * inv;
    *(float4*)(op + dt * 16 + quad * 4) = o;
  }
}

extern "C" void kernel_launch(void* const* d_in, const int* in_sizes, int n_in,
                              void* d_out, int out_size, void* d_ws, size_t ws_size,
                              hipStream_t stream) {
  const float* q = (const float*)d_in[0];
  const float* k = (const float*)d_in[1];
  const float* v = (const float*)d_in[2];
  // d_in[3] (mask) is guaranteed tril-causal; handled analytically.
  float* out = (float*)d_out;

  unsigned short* kws = (unsigned short*)d_ws;           // 16 MiB
  unsigned short* vws = kws + NELEM;                     // 16 MiB (transposed)

  prep<<<3072, 256, 0, stream>>>(k, v, kws, vws);
  fattn<<<512, 512, 0, stream>>>(q, kws, vws, out);
}

// Round 10
// 197.762 us; speedup vs baseline: 1.0207x; 1.0207x over previous
//
#include <hip/hip_runtime.h>

// FlashAttention fwd, causal, no scale. B=2,H=16,S=2048,D=128, fp32 in/out.
// R4 design: S^T orientation (mfma(kf,qf)) so each lane owns a full query row.
// R12 (base, 77us): single-barrier double-buffer @512t BM=128.
// R7/R8/R13 FAILED: permlane16/32_swap-based reduce broke 3x (identical
//   absmax 1.28e5 = 2x fp16-max). Primitive BANNED this session.
// R14: eliminate the P transpose with ZERO cross-lane ops. MFMA's k-axis is
//   a reduction -> any key permutation is legal if A (V^T) and B (P) agree.
//   Choose B-frag elem j of slice ch = key ch*32+(j>>2)*16+q*4+(j&3) (bit
//   rotate, bijective). Then B-frag = {pkd[2ch][0],pkd[2ch][1],
//   pkd[2ch+1][0],pkd[2ch+1][1]} DIRECTLY from softmax registers. Matching
//   A-side perm applied in PREP (V^T stored key-permuted within each
//   64-block: key s -> pos ch*32+q*8+half*4+r; 16B store -> 2x 8B stores,
//   negligible on BW-bound prep). fattn staging + PV ds_read byte-identical.
//   Deletes per iter: 4 ds_write + 2 ds_read + serial softmax->PV LDS wait
//   + sP bank conflicts; LDS 80KB->64KB.
// History: R1 bf16 fail; R2 scratch demotion; R3 244; R4 94/215; R5 dbuf@256t
// 102; R6 86.5; R9 83.4/205; R10 89; R11 80.3/201.7; R12 77/201.9
// (MfmaUtil 18 = FLOP-exact, ~55% idle = latency-bound).

#define SQ 2048
#define DH 128
#define BM 128
#define BN 64
#define NELEM 8388608   // B*H*S*D

typedef _Float16 f16x8 __attribute__((ext_vector_type(8)));
typedef float f32x4 __attribute__((ext_vector_type(4)));
typedef unsigned short u16x8 __attribute__((ext_vector_type(8)));
typedef unsigned int u32x4 __attribute__((ext_vector_type(4)));
typedef unsigned int u32x2 __attribute__((ext_vector_type(2)));

__device__ __forceinline__ unsigned short f2h(float f) {
  return __builtin_bit_cast(unsigned short, (_Float16)f);   // v_cvt_f16_f32 RNE
}

// ---------------- pre-kernel: K fp32->fp16 flat; V fp32 -> Vt[bh][d][s] fp16
// V^T stored with keys PERMUTED within each 64-aligned block:
//   key s (ch=s>>5, half=(s>>4)&1, q=(s&15)>>2, r=s&3) -> pos ch*32+q*8+half*4+r
// so that fattn's PV b128 read (group ch*4+quad) yields keys
// {ch*32+q*4+0..3, ch*32+16+q*4+0..3} = softmax's register-resident P order.
__global__ __launch_bounds__(256) void prep(const float* __restrict__ k,
                                            const float* __restrict__ v,
                                            unsigned short* __restrict__ ko,
                                            unsigned short* __restrict__ vt) {
  const int tid = threadIdx.x;
  const int bx = blockIdx.x;
  if (bx < 1024) {
    // V transpose tile: 64 s x 128 d
    __shared__ unsigned short lv[64 * 132];   // pad 128->132 to break bank stride
    const int bh = bx >> 5;
    const int s0 = (bx & 31) * 64;
    const float* vs = v + ((size_t)bh * SQ + s0) * DH;
    #pragma unroll
    for (int it = 0; it < 8; ++it) {
      int fi = it * 256 + tid;
      int sL = fi >> 5;
      int dL = (fi & 31) * 4;
      float4 val = *(const float4*)(vs + (size_t)sL * DH + dL);
      ushort4 o;
      o.x = f2h(val.x); o.y = f2h(val.y); o.z = f2h(val.z); o.w = f2h(val.w);
      *(ushort4*)(lv + sL * 132 + dL) = o;
    }
    __syncthreads();
    // store: 8 keys sg*8+j -> permuted positions pos0+{0..3}, pos0+8+{0..3}
    #pragma unroll
    for (int it = 0; it < 4; ++it) {
      int ci = it * 256 + tid;     // 1024 chunks: dL = ci>>3, sg = ci&7
      int dL = ci >> 3;
      int sg = ci & 7;
      u16x8 o;
      #pragma unroll
      for (int j = 0; j < 8; ++j) o[j] = lv[(sg * 8 + j) * 132 + dL];
      // keys sg*8+j: ch=sg>>2, q1=sg&1, half=(sg>>1)&1, q0=j>>2, r=j&3
      // pos = ch*32 + (q1*2+q0)*8 + half*4 + r
      int pos0 = (sg >> 2) * 32 + (sg & 1) * 16 + ((sg >> 1) & 1) * 4;
      unsigned short* vdst = vt + ((size_t)bh * DH + dL) * SQ + s0;
      *(ushort4*)(vdst + pos0)     = (ushort4){o[0], o[1], o[2], o[3]};
      *(ushort4*)(vdst + pos0 + 8) = (ushort4){o[4], o[5], o[6], o[7]};
    }
  } else {
    // K conversion: 2048 blocks grid-stride over NELEM/4 float4 chunks
    const int NT = NELEM / 4;
    for (int i = (bx - 1024) * 256 + tid; i < NT; i += 2048 * 256) {
      float4 val = ((const float4*)k)[i];
      ushort4 o;
      o.x = f2h(val.x); o.y = f2h(val.y); o.z = f2h(val.z); o.w = f2h(val.w);
      ((ushort4*)ko)[i] = o;
    }
  }
}

// ---------------- main flash-attention kernel ----------------
// Grid 512, 512 threads (8 waves). xcd = t&7 owns bh in [xcd*4, xcd*4+4);
// per-XCD: cu = (t>>3)&31 -> bh_l = cu>>3, j = cu&7; round (t>>8): qb = j or
// 15-j, so each CU's 2 WGs total 34 kt-units.
// LDS map: buf0 {K [0,16K), V [16K,32K)}, buf1 {K [32K,48K), V [48K,64K)}.
// No sP (P feeds PV directly from registers). Q prologue stages into buf0.
__global__ __launch_bounds__(512, 4) void fattn(const float* __restrict__ Qf,
                                                const unsigned short* __restrict__ Kh,
                                                const unsigned short* __restrict__ Vth,
                                                float* __restrict__ Out) {
  __shared__ char smem[65536];
  const int tid  = threadIdx.x;
  const int wave = tid >> 6;                // 0..7
  const int lane = tid & 63;
  const int quad = lane >> 4;
  const int c    = lane & 15;

  // block swizzle: XCD bh-affinity + per-CU (j, 15-j) pairing
  const int t     = (int)blockIdx.x;
  const int xcd   = t & 7;
  const int idx   = t >> 3;                 // 0..63
  const int cu    = idx & 31;
  const int round = idx >> 5;               // 0..1
  const int bh_l  = cu >> 3;                // 0..3
  const int j     = cu & 7;
  const int qb    = round ? (15 - j) : j;   // 0..15
  const int bh    = xcd * 4 + bh_l;
  const int rowbase = qb * BM;

  // ---- stage Q (fp32 -> fp16, pre-scaled by log2e) into buf0 region ----
  const float L2E = 1.44269504088896f;
  const float* Qg = Qf + ((size_t)bh * SQ + rowbase) * DH;
  #pragma unroll
  for (int it = 0; it < 8; ++it) {
    int gi  = it * 512 + tid;      // 4096 units of 4 floats (128 rows x 32)
    int row = gi >> 5;             // 0..127
    int sub = gi & 31;             // 4-float unit within row
    float4 qv = *(const float4*)(Qg + (size_t)row * DH + sub * 4);
    ushort4 h;
    h.x = f2h(qv.x * L2E); h.y = f2h(qv.y * L2E);
    h.z = f2h(qv.z * L2E); h.w = f2h(qv.w * L2E);
    int gr = (sub >> 1) ^ (row & 7);        // 16B-group swizzle
    *(ushort4*)(smem + row * 256 + gr * 16 + (sub & 1) * 8) = h;
  }
  __syncthreads();
  f16x8 qf[4];
  {
    int rl = wave * 16 + c;                 // wave's row (tile-local, 0..127)
    #pragma unroll
    for (int ch = 0; ch < 4; ++ch) {
      int gr = (ch * 4 + quad) ^ (c & 7);   // rl&7 == c&7
      qf[ch] = *(const f16x8*)(smem + rl * 256 + gr * 16);
    }
  }

  // ---- per-thread staging source bases (kt=0); invariant across it-steps:
  // K: 1024 chunks, key = it*32 + (tid>>4), dg = (tid&15)^(key&7) (32%8==0)
  // V: 1024 chunks, d = it*64 + (tid>>3),  kg = (tid&7)^(d&7)     (64%8==0)
  const unsigned short* Kbase = Kh + (size_t)bh * SQ * DH;
  const unsigned short* Vbase = Vth + (size_t)bh * DH * SQ;
  const unsigned short* Ksrc = Kbase + (size_t)(tid >> 4) * DH
                             + ((tid & 15) ^ ((tid >> 4) & 7)) * 8;
  const unsigned short* Vsrc = Vbase + (size_t)(tid >> 3) * SQ
                             + ((tid & 7) ^ ((tid >> 3) & 7)) * 8;

  // ---- kt=0 tile -> regs (issued while Q-region still being read) ----
  u32x4 kreg[2], vreg[2];
  #pragma unroll
  for (int it = 0; it < 2; ++it)
    kreg[it] = *(const u32x4*)(Ksrc + it * (32 * DH));
  #pragma unroll
  for (int it = 0; it < 2; ++it)
    vreg[it] = *(const u32x4*)(Vsrc + it * (64 * SQ));
  __syncthreads();   // all waves done reading Q area (loads in flight)

  // ---- write kt=0 into buf0 (linear dest, pre-swizzled source order) ----
  #pragma unroll
  for (int it = 0; it < 2; ++it)
    *(u32x4*)(smem + it * 8192 + tid * 16) = kreg[it];
  #pragma unroll
  for (int it = 0; it < 2; ++it)
    *(u32x4*)(smem + 16384 + it * 8192 + tid * 16) = vreg[it];
  __syncthreads();

  f32x4 acc[8];                             // O^T: d = dt*16+quad*4+r, row = c
  #pragma unroll
  for (int dt = 0; dt < 8; ++dt) acc[dt] = (f32x4){0.f, 0.f, 0.f, 0.f};
  float mo = -1e30f, lrow = 0.f;            // row stats, log2 domain (row = c)

  const int nkt = 2 * qb + 2;
  int cur = 0;
  for (int kt = 0; kt < nkt; ++kt) {
    const bool hn = (kt + 1 < nkt);
    char* sK = smem + (cur << 15);
    char* sV = sK + 16384;

    // ---- prefetch kt+1 into REGISTERS; vmcnt wait lands at the ds_write
    // AFTER PV (covered by the whole iteration's compute) ----
    if (hn) {
      const unsigned short* Kn = Ksrc + (size_t)(kt + 1) * (BN * DH);
      const unsigned short* Vn = Vsrc + (size_t)(kt + 1) * BN;
      #pragma unroll
      for (int it = 0; it < 2; ++it)
        kreg[it] = *(const u32x4*)(Kn + it * (32 * DH));
      #pragma unroll
      for (int it = 0; it < 2; ++it)
        vreg[it] = *(const u32x4*)(Vn + it * (64 * SQ));
    }
    __builtin_amdgcn_sched_barrier(0);   // pin load issue before compute

    // ---- diagonal classification (two boundary kt tiles per block) ----
    const bool dg1 = (kt == 2 * qb);        // rows 0..63 on diagonal
    const bool dg2 = (kt == 2 * qb + 1);    // rows 64..127 on diagonal
    int ntmax = 3, chmax = 1, rl = 1000;    // defaults: full, no mask
    if (dg1 && wave < 4) { ntmax = wave; chmax = wave >> 1; rl = wave * 16 + c; }
    if (dg2) {
      int w2 = wave - 4;
      if (w2 < 0) { ntmax = -1; chmax = -1; rl = -1; }       // fully masked
      else        { ntmax = w2; chmax = w2 >> 1; rl = w2 * 16 + c; }
    }

    // ---- S^T = K Q^T: D[m=key][n=row]; col=c=row, key = nt*16+quad*4+r ----
    f32x4 sc[4];
    #pragma unroll
    for (int nt = 0; nt < 4; ++nt) sc[nt] = (f32x4){0.f, 0.f, 0.f, 0.f};
    __builtin_amdgcn_s_setprio(1);
    #pragma unroll
    for (int nt = 0; nt < 4; ++nt) {
      if (nt <= ntmax) {
        int keyl = nt * 16 + c;
        #pragma unroll
        for (int ch = 0; ch < 4; ++ch) {
          int gr = (ch * 4 + quad) ^ (c & 7);   // keyl&7 == c&7
          f16x8 kf = *(const f16x8*)(sK + keyl * 256 + gr * 16);
          sc[nt] = __builtin_amdgcn_mfma_f32_16x16x32_f16(kf, qf[ch], sc[nt], 0, 0, 0);
        }
      }
    }
    __builtin_amdgcn_s_setprio(0);

    // ---- causal mask (rl=1000: none; rl=-1: all; else diagonal) ----
    // NO barrier here: sK/sV[cur] stay valid all iteration (dbuf).
    if (rl < 1000) {
      #pragma unroll
      for (int nt = 0; nt < 4; ++nt)
        #pragma unroll
        for (int r = 0; r < 4; ++r)
          if (nt * 16 + quad * 4 + r > rl) sc[nt][r] = -1e30f;
    }

    // ---- online softmax (log2 domain): tree-max + shfl_xor quad reduce ----
    f32x4 ta, tb;
    #pragma unroll
    for (int r = 0; r < 4; ++r) {
      ta[r] = fmaxf(sc[0][r], sc[1][r]);
      tb[r] = fmaxf(sc[2][r], sc[3][r]);
    }
    float cm = fmaxf(fmaxf(fmaxf(ta[0], tb[0]), fmaxf(ta[1], tb[1])),
                     fmaxf(fmaxf(ta[2], tb[2]), fmaxf(ta[3], tb[3])));
    cm = fmaxf(cm, __shfl_xor(cm, 16));
    cm = fmaxf(cm, __shfl_xor(cm, 32));
    const bool keep = __all(cm <= mo + 8.0f) != 0;   // T13 defer-max, P<=2^8
    const float mn = keep ? mo : fmaxf(mo, cm);

    float ps[4];
    u32x2 pkd[4];
    #pragma unroll
    for (int nt = 0; nt < 4; ++nt) {
      float p0 = __builtin_amdgcn_exp2f(sc[nt][0] - mn);
      float p1 = __builtin_amdgcn_exp2f(sc[nt][1] - mn);
      float p2 = __builtin_amdgcn_exp2f(sc[nt][2] - mn);
      float p3 = __builtin_amdgcn_exp2f(sc[nt][3] - mn);
      ps[nt] = (p0 + p1) + (p2 + p3);
      pkd[nt][0] = __builtin_bit_cast(unsigned int, __builtin_amdgcn_cvt_pkrtz(p0, p1));
      pkd[nt][1] = __builtin_bit_cast(unsigned int, __builtin_amdgcn_cvt_pkrtz(p2, p3));
    }
    float rs = (ps[0] + ps[1]) + (ps[2] + ps[3]);
    rs += __shfl_xor(rs, 16);
    rs += __shfl_xor(rs, 32);

    if (keep) {
      lrow += rs;            // mn == mo everywhere: no rescale needed
    } else {
      const float al = __builtin_amdgcn_exp2f(mo - mn);
      lrow = lrow * al + rs;
      mo = mn;
      #pragma unroll
      for (int dt = 0; dt < 8; ++dt) acc[dt] *= al;
    }

    // ---- O^T += Vt * P: B-frag = pkd concat (V^T pre-permuted to match:
    // B elem j of slice ch = key ch*32+(j>>2)*16+q*4+(j&3)) ----
    __builtin_amdgcn_s_setprio(1);
    #pragma unroll
    for (int ch = 0; ch < 2; ++ch) {
      if (ch <= chmax) {
        u32x4 pw = (u32x4){pkd[2 * ch][0], pkd[2 * ch][1],
                           pkd[2 * ch + 1][0], pkd[2 * ch + 1][1]};
        f16x8 pf = __builtin_bit_cast(f16x8, pw);
        #pragma unroll
        for (int dt = 0; dt < 8; ++dt) {
          int d  = dt * 16 + c;
          int gr = (ch * 4 + quad) ^ (c & 7);   // d&7 == c&7
          f16x8 vf = *(const f16x8*)(sV + d * 128 + gr * 16);
          acc[dt] = __builtin_amdgcn_mfma_f32_16x16x32_f16(vf, pf, acc[dt], 0, 0, 0);
        }
      }
    }
    __builtin_amdgcn_s_setprio(0);

    // ---- stage kt+1 into the OTHER buffer; single barrier per iteration ----
    if (hn) {
      char* nK = smem + ((cur ^ 1) << 15);
      #pragma unroll
      for (int it = 0; it < 2; ++it)
        *(u32x4*)(nK + it * 8192 + tid * 16) = kreg[it];
      #pragma unroll
      for (int it = 0; it < 2; ++it)
        *(u32x4*)(nK + 16384 + it * 8192 + tid * 16) = vreg[it];
      __syncthreads();   // publishes buf[cur^1]; fences buf[cur] reuse
    }
    cur ^= 1;
  }

  // ---- epilogue: O[row][d] = acc / l; float4 per dt ----
  const float inv = 1.0f / lrow;
  const int rowg = rowbase + wave * 16 + c;
  float* op = Out + ((size_t)bh * SQ + rowg) * DH;
  #pragma unroll
  for (int dt = 0; dt < 8; ++dt) {
    float4 o;
    o.x = acc[dt][0] * inv;
    o.y = acc[dt][1] * inv;
    o.z = acc[dt][2] * inv;
    o.w = acc[dt][3] * inv;
    *(float4*)(op + dt * 16 + quad * 4) = o;
  }
}

extern "C" void kernel_launch(void* const* d_in, const int* in_sizes, int n_in,
                              void* d_out, int out_size, void* d_ws, size_t ws_size,
                              hipStream_t stream) {
  const float* q = (const float*)d_in[0];
  const float* k = (const float*)d_in[1];
  const float* v = (const float*)d_in[2];
  // d_in[3] (mask) is guaranteed tril-causal; handled analytically.
  float* out = (float*)d_out;

  unsigned short* kws = (unsigned short*)d_ws;           // 16 MiB
  unsigned short* vws = kws + NELEM;                     // 16 MiB (transposed)

  prep<<<3072, 256, 0, stream>>>(k, v, kws, vws);
  fattn<<<512, 512, 0, stream>>>(q, kws, vws, out);
}